// Round 1
// baseline (483.259 us; speedup 1.0000x reference)
//
#include <hip/hip_runtime.h>

// GraphConvolution (Chebyshev K=5) on MI355X.
// Internal layout choice: xs_k stored as [M][b*FIN+f] (vs reference's [M][f*B+b]);
// SpMM is per-column independent so any consistent permutation is valid, and this
// one lets k=0 be read straight from x[B,M,FIN] with contiguous float4s.
//
// Pipeline per call (deterministic work; tiny fp-reassociation from scatter atomics):
//   memset counts -> hist -> scan(3 kernels) -> memset fill -> scatter
//   -> spmm x1 = L x0           (gather from x directly)
//   -> spmm x2 = 2 L x1 - x0    (sub from x directly)
//   -> spmm x3 = 2 L x2 - x1
//   -> spmm x4 = 2 L x3 - x2
//   -> gemm  out[b,m,:] = sum_{k,f} xs_k[m][b*16+f] * kernel[f*K+k,:] + bias

constexpr int M   = 49152;
constexpr int B   = 16;
constexpr int FIN = 16;
constexpr int F1  = 32;
constexpr int K   = 5;
constexpr int FB  = B * FIN;            // 256 features per internal row
constexpr int XBS = M * FIN;            // 786432: per-b stride in x[B,M,FIN]

#define DEVFN __device__ __forceinline__

// ---------------- CSR build ----------------

__global__ __launch_bounds__(256) void hist_kernel(const int* __restrict__ rows,
                                                   int* __restrict__ counts, int nnz) {
  int i = blockIdx.x * 256 + threadIdx.x;
  if (i < nnz) atomicAdd(&counts[rows[i]], 1);
}

DEVFN int wave_incl_scan(int v, int lane) {
#pragma unroll
  for (int off = 1; off < 64; off <<= 1) {
    int t = __shfl_up(v, off);
    if (lane >= off) v += t;
  }
  return v;
}

// 48 blocks x 1024: per-block inclusive scan of counts -> row_ptr[i+1], block total -> partials
__global__ __launch_bounds__(1024) void scan_blocks(const int* __restrict__ counts,
                                                    int* __restrict__ row_ptr,
                                                    int* __restrict__ partials) {
  __shared__ int wsum[16];
  int tid = threadIdx.x, lane = tid & 63, w = tid >> 6;
  int i = blockIdx.x * 1024 + tid;
  int s = wave_incl_scan(counts[i], lane);
  if (lane == 63) wsum[w] = s;
  __syncthreads();
  if (tid < 16) {
    int t = wsum[tid];
#pragma unroll
    for (int off = 1; off < 16; off <<= 1) {
      int u = __shfl_up(t, off);
      if (tid >= off) t += u;
    }
    wsum[tid] = t;
  }
  __syncthreads();
  int base = (w > 0) ? wsum[w - 1] : 0;
  s += base;
  row_ptr[i + 1] = s;
  if (tid == 1023) partials[blockIdx.x] = s;
}

__global__ void scan_partials_kernel(int* __restrict__ partials,
                                     int* __restrict__ row_ptr, int nblk) {
  int lane = threadIdx.x;  // 64 threads
  int v = (lane < nblk) ? partials[lane] : 0;
  v = wave_incl_scan(v, lane);
  if (lane < nblk) partials[lane] = v;
  if (lane == 0) row_ptr[0] = 0;
}

__global__ __launch_bounds__(1024) void scan_add_kernel(int* __restrict__ row_ptr,
                                                        const int* __restrict__ partials) {
  if (blockIdx.x == 0) return;
  int i = blockIdx.x * 1024 + threadIdx.x;
  row_ptr[i + 1] += partials[blockIdx.x - 1];
}

__global__ __launch_bounds__(256) void scatter_kernel(const int* __restrict__ rows,
                                                      const int* __restrict__ cols,
                                                      const float* __restrict__ vals,
                                                      const int* __restrict__ row_ptr,
                                                      int* __restrict__ fill,
                                                      int2* __restrict__ cv, int nnz) {
  int i = blockIdx.x * 256 + threadIdx.x;
  if (i < nnz) {
    int r = rows[i];
    int pos = row_ptr[r] + atomicAdd(&fill[r], 1);
    cv[pos] = make_int2(cols[i], __float_as_int(vals[i]));
  }
}

// ---------------- SpMM (one wave per output row) ----------------
// y[m,:] = scale * sum_e val_e * X[col_e,:]  (- sub[m,:] when SUB)
// FROM_X / SUB_FROM_X: operand lives in x[B,M,FIN] layout instead of [M][256].

template <bool FROM_X, bool SUB, bool SUB_FROM_X>
__global__ __launch_bounds__(256) void spmm_kernel(const float* __restrict__ gsrc,
                                                   const float* __restrict__ ssrc,
                                                   float* __restrict__ y,
                                                   const int* __restrict__ row_ptr,
                                                   const int2* __restrict__ cv) {
  int lane = threadIdx.x & 63;
  int m = blockIdx.x * 4 + (threadIdx.x >> 6);
  int beg = row_ptr[m], end = row_ptr[m + 1];
  int b = lane >> 2;                 // for x-layout accesses
  int f0 = (lane & 3) * 4;
  float4 acc = make_float4(0.f, 0.f, 0.f, 0.f);
  for (int e = beg; e < end; ++e) {
    int2 p = cv[e];
    int c = p.x;
    float v = __int_as_float(p.y);
    float4 xv;
    if (FROM_X)
      xv = *(const float4*)(gsrc + (size_t)b * XBS + (size_t)c * FIN + f0);
    else
      xv = *(const float4*)(gsrc + (size_t)c * FB + lane * 4);
    acc.x = fmaf(v, xv.x, acc.x);
    acc.y = fmaf(v, xv.y, acc.y);
    acc.z = fmaf(v, xv.z, acc.z);
    acc.w = fmaf(v, xv.w, acc.w);
  }
  if (SUB) {
    float4 s;
    if (SUB_FROM_X)
      s = *(const float4*)(ssrc + (size_t)b * XBS + (size_t)m * FIN + f0);
    else
      s = *(const float4*)(ssrc + (size_t)m * FB + lane * 4);
    acc.x = fmaf(2.f, acc.x, -s.x);
    acc.y = fmaf(2.f, acc.y, -s.y);
    acc.z = fmaf(2.f, acc.z, -s.z);
    acc.w = fmaf(2.f, acc.w, -s.w);
  }
  *(float4*)(y + (size_t)m * FB + lane * 4) = acc;
}

// ---------------- Final contraction ----------------
// Block = 256 threads = 4 waves; each wave handles 2 m-rows (one per 32-lane half).
// lane: o = lane&31 (output channel), h = lane>>5 (which m of the pair).
// acc[b] over all 16 b. kernel reordered in LDS as kl[k][f][o] (conflict-free reads);
// xs rows staged in LDS, read as broadcast float4 (2 distinct addrs/wave = free).

__global__ __launch_bounds__(256) void cheb_gemm(const float* __restrict__ x,
                                                 const float* __restrict__ x1b,
                                                 const float* __restrict__ x2b,
                                                 const float* __restrict__ x3b,
                                                 const float* __restrict__ x4b,
                                                 const float* __restrict__ kern,
                                                 const float* __restrict__ bias,
                                                 float* __restrict__ out) {
  __shared__ float kl[K][FIN][F1];   // 10 KB
  __shared__ float xl[8][K][FB];     // 40 KB: 8 m-rows per block
  int tid = threadIdx.x;
  for (int i = tid; i < K * FIN * F1; i += 256) {
    int o = i & 31, rest = i >> 5;
    int f = rest & 15, k = rest >> 4;
    kl[k][f][o] = kern[(f * K + k) * F1 + o];
  }
  int wave = tid >> 6, lane = tid & 63;
  int h = lane >> 5, o = lane & 31;
  int m0 = blockIdx.x * 8 + 2 * wave;   // wave's first m

  // stage xs rows: per slot s (2 rows per wave), 5 k-planes, one float4/lane each
  {
    int b = lane >> 2, f4 = (lane & 3) * 4;
#pragma unroll
    for (int s = 0; s < 2; ++s) {
      int m = m0 + s;
      int slot = 2 * wave + s;
      *(float4*)(&xl[slot][0][lane * 4]) =
          *(const float4*)(x + (size_t)b * XBS + (size_t)m * FIN + f4);
      *(float4*)(&xl[slot][1][lane * 4]) = *(const float4*)(x1b + (size_t)m * FB + lane * 4);
      *(float4*)(&xl[slot][2][lane * 4]) = *(const float4*)(x2b + (size_t)m * FB + lane * 4);
      *(float4*)(&xl[slot][3][lane * 4]) = *(const float4*)(x3b + (size_t)m * FB + lane * 4);
      *(float4*)(&xl[slot][4][lane * 4]) = *(const float4*)(x4b + (size_t)m * FB + lane * 4);
    }
  }
  __syncthreads();

  float acc[16];
  float bs = bias[o];
#pragma unroll
  for (int b = 0; b < 16; ++b) acc[b] = bs;

  int slot = 2 * wave + h;
#pragma unroll
  for (int k = 0; k < K; ++k) {
#pragma unroll
    for (int f4 = 0; f4 < 4; ++f4) {
      float kv0 = kl[k][f4 * 4 + 0][o];
      float kv1 = kl[k][f4 * 4 + 1][o];
      float kv2 = kl[k][f4 * 4 + 2][o];
      float kv3 = kl[k][f4 * 4 + 3][o];
#pragma unroll
      for (int b = 0; b < 16; ++b) {
        const float4 xv = *(const float4*)(&xl[slot][k][b * 16 + f4 * 4]);
        acc[b] = fmaf(xv.x, kv0, acc[b]);
        acc[b] = fmaf(xv.y, kv1, acc[b]);
        acc[b] = fmaf(xv.z, kv2, acc[b]);
        acc[b] = fmaf(xv.w, kv3, acc[b]);
      }
    }
  }

  int m = m0 + h;
#pragma unroll
  for (int b = 0; b < 16; ++b)
    out[((size_t)b * M + m) * F1 + o] = acc[b];
}

// ---------------- launch ----------------

extern "C" void kernel_launch(void* const* d_in, const int* in_sizes, int n_in,
                              void* d_out, int out_size, void* d_ws, size_t ws_size,
                              hipStream_t stream) {
  const float* x    = (const float*)d_in[0];
  const int*   rows = (const int*)d_in[1];
  const int*   cols = (const int*)d_in[2];
  const float* vals = (const float*)d_in[3];
  const float* kern = (const float*)d_in[4];
  const float* bias = (const float*)d_in[5];
  float* out = (float*)d_out;
  int nnz = in_sizes[1];

  // workspace layout (~195.4 MiB total)
  const size_t BUF = (size_t)M * FB;              // 12,582,912 floats
  float* buf1 = (float*)d_ws;
  float* buf2 = buf1 + BUF;
  float* buf3 = buf2 + BUF;
  float* buf4 = buf3 + BUF;
  int* row_ptr  = (int*)(buf4 + BUF);             // M+1 (padded to M+256)
  int* counts   = row_ptr + (M + 256);            // M (doubles as scatter fill)
  int* partials = counts + M;                     // 48 (padded to 256)
  int2* cv      = (int2*)(partials + 256);        // NNZ packed (col, val)

  int nblk1024 = M / 1024;                        // 48
  int nblkNnz  = (nnz + 255) / 256;

  hipMemsetAsync(counts, 0, (size_t)M * 4, stream);
  hist_kernel<<<nblkNnz, 256, 0, stream>>>(rows, counts, nnz);
  scan_blocks<<<nblk1024, 1024, 0, stream>>>(counts, row_ptr, partials);
  scan_partials_kernel<<<1, 64, 0, stream>>>(partials, row_ptr, nblk1024);
  scan_add_kernel<<<nblk1024, 1024, 0, stream>>>(row_ptr, partials);
  hipMemsetAsync(counts, 0, (size_t)M * 4, stream);
  scatter_kernel<<<nblkNnz, 256, 0, stream>>>(rows, cols, vals, row_ptr, counts, cv, nnz);

  // Chebyshev recurrence
  spmm_kernel<true, false, false><<<M / 4, 256, 0, stream>>>(x, nullptr, buf1, row_ptr, cv);
  spmm_kernel<false, true, true><<<M / 4, 256, 0, stream>>>(buf1, x, buf2, row_ptr, cv);
  spmm_kernel<false, true, false><<<M / 4, 256, 0, stream>>>(buf2, buf1, buf3, row_ptr, cv);
  spmm_kernel<false, true, false><<<M / 4, 256, 0, stream>>>(buf3, buf2, buf4, row_ptr, cv);

  // final contraction + bias
  cheb_gemm<<<M / 8, 256, 0, stream>>>(x, buf1, buf2, buf3, buf4, kern, bias, out);

  (void)n_in; (void)out_size; (void)ws_size; (void)in_sizes;
}

// Round 2
// 362.877 us; speedup vs baseline: 1.3317x; 1.3317x over previous
//
#include <hip/hip_runtime.h>

// GraphConvolution (Chebyshev K=5) on MI355X — round 2.
// Change vs round 1: all Chebyshev intermediates stored as bf16 [M][256]
// (512 B/row instead of 1 KB) -> halves the random-gather traffic that
// dominated (4 SpMMs x 367 MB fetch @ ~3 TB/s = 4 x 123 us). fp32 accumulate.
//
// Pipeline:
//   transform x -> x0b (bf16 [M][b*16+f])
//   CSR build: memset -> hist -> scan(3) -> memset -> scatter
//   spmm x1 = L x0            (all operands bf16, fp32 accum)
//   spmm x2 = 2 L x1 - x0
//   spmm x3 = 2 L x2 - x1
//   spmm x4 = 2 L x3 - x2
//   gemm out[b,m,:] = sum_{k,f} xs_k[m][b*16+f] * kernel[f*K+k,:] + bias (fp32 out)

constexpr int M   = 49152;
constexpr int B   = 16;
constexpr int FIN = 16;
constexpr int F1  = 32;
constexpr int K   = 5;
constexpr int FB  = B * FIN;            // 256 features per internal row
constexpr int RW  = FB / 4;             // 64 ushort4 per row
constexpr int XBS = M * FIN;            // per-b stride in x[B,M,FIN]

#define DEVFN __device__ __forceinline__

DEVFN float bf2f(unsigned short h) {
  union { unsigned int u; float f; } v;
  v.u = (unsigned int)h << 16;
  return v.f;
}
DEVFN unsigned short f2bf(float f) {   // round-to-nearest-even (no NaN inputs here)
  union { float f; unsigned int u; } v;
  v.f = f;
  unsigned int r = (v.u + 0x7FFFu + ((v.u >> 16) & 1u)) >> 16;
  return (unsigned short)r;
}
DEVFN float4 bf4(ushort4 u) {
  return make_float4(bf2f(u.x), bf2f(u.y), bf2f(u.z), bf2f(u.w));
}

// ---------------- x -> bf16 [M][256] ----------------

__global__ __launch_bounds__(256) void transform_x(const float* __restrict__ x,
                                                   ushort4* __restrict__ x0b) {
  int lane = threadIdx.x & 63;
  int m = blockIdx.x * 4 + (threadIdx.x >> 6);
  int b = lane >> 2, f0 = (lane & 3) * 4;
  float4 v = *(const float4*)(x + (size_t)b * XBS + (size_t)m * FIN + f0);
  x0b[(size_t)m * RW + lane] = make_ushort4(f2bf(v.x), f2bf(v.y), f2bf(v.z), f2bf(v.w));
}

// ---------------- CSR build ----------------

__global__ __launch_bounds__(256) void hist_kernel(const int* __restrict__ rows,
                                                   int* __restrict__ counts, int nnz) {
  int i = blockIdx.x * 256 + threadIdx.x;
  if (i < nnz) atomicAdd(&counts[rows[i]], 1);
}

DEVFN int wave_incl_scan(int v, int lane) {
#pragma unroll
  for (int off = 1; off < 64; off <<= 1) {
    int t = __shfl_up(v, off);
    if (lane >= off) v += t;
  }
  return v;
}

__global__ __launch_bounds__(1024) void scan_blocks(const int* __restrict__ counts,
                                                    int* __restrict__ row_ptr,
                                                    int* __restrict__ partials) {
  __shared__ int wsum[16];
  int tid = threadIdx.x, lane = tid & 63, w = tid >> 6;
  int i = blockIdx.x * 1024 + tid;
  int s = wave_incl_scan(counts[i], lane);
  if (lane == 63) wsum[w] = s;
  __syncthreads();
  if (tid < 16) {
    int t = wsum[tid];
#pragma unroll
    for (int off = 1; off < 16; off <<= 1) {
      int u = __shfl_up(t, off);
      if (tid >= off) t += u;
    }
    wsum[tid] = t;
  }
  __syncthreads();
  int base = (w > 0) ? wsum[w - 1] : 0;
  s += base;
  row_ptr[i + 1] = s;
  if (tid == 1023) partials[blockIdx.x] = s;
}

__global__ void scan_partials_kernel(int* __restrict__ partials,
                                     int* __restrict__ row_ptr, int nblk) {
  int lane = threadIdx.x;  // 64 threads
  int v = (lane < nblk) ? partials[lane] : 0;
  v = wave_incl_scan(v, lane);
  if (lane < nblk) partials[lane] = v;
  if (lane == 0) row_ptr[0] = 0;
}

__global__ __launch_bounds__(1024) void scan_add_kernel(int* __restrict__ row_ptr,
                                                        const int* __restrict__ partials) {
  if (blockIdx.x == 0) return;
  int i = blockIdx.x * 1024 + threadIdx.x;
  row_ptr[i + 1] += partials[blockIdx.x - 1];
}

__global__ __launch_bounds__(256) void scatter_kernel(const int* __restrict__ rows,
                                                      const int* __restrict__ cols,
                                                      const float* __restrict__ vals,
                                                      const int* __restrict__ row_ptr,
                                                      int* __restrict__ fill,
                                                      int2* __restrict__ cv, int nnz) {
  int i = blockIdx.x * 256 + threadIdx.x;
  if (i < nnz) {
    int r = rows[i];
    int pos = row_ptr[r] + atomicAdd(&fill[r], 1);
    cv[pos] = make_int2(cols[i], __float_as_int(vals[i]));
  }
}

// ---------------- SpMM (one wave per output row, bf16 rows) ----------------
// y[m,:] = sum_e val_e * X[col_e,:]            (SUB=false)
// y[m,:] = 2*sum_e val_e * X[col_e,:] - S[m,:] (SUB=true)

template <bool SUB>
__global__ __launch_bounds__(256) void spmm_bf16(const ushort4* __restrict__ gsrc,
                                                 const ushort4* __restrict__ ssrc,
                                                 ushort4* __restrict__ y,
                                                 const int* __restrict__ row_ptr,
                                                 const int2* __restrict__ cv) {
  int lane = threadIdx.x & 63;
  int m = blockIdx.x * 4 + (threadIdx.x >> 6);
  int beg = row_ptr[m], end = row_ptr[m + 1];
  float a0 = 0.f, a1 = 0.f, a2 = 0.f, a3 = 0.f;
  for (int e = beg; e < end; ++e) {
    int2 p = cv[e];
    float v = __int_as_float(p.y);
    ushort4 xv = gsrc[(size_t)p.x * RW + lane];
    a0 = fmaf(v, bf2f(xv.x), a0);
    a1 = fmaf(v, bf2f(xv.y), a1);
    a2 = fmaf(v, bf2f(xv.z), a2);
    a3 = fmaf(v, bf2f(xv.w), a3);
  }
  if (SUB) {
    float4 s = bf4(ssrc[(size_t)m * RW + lane]);
    a0 = fmaf(2.f, a0, -s.x);
    a1 = fmaf(2.f, a1, -s.y);
    a2 = fmaf(2.f, a2, -s.z);
    a3 = fmaf(2.f, a3, -s.w);
  }
  y[(size_t)m * RW + lane] = make_ushort4(f2bf(a0), f2bf(a1), f2bf(a2), f2bf(a3));
}

// ---------------- Final contraction ----------------
// Block = 256 threads = 4 waves; each wave handles 2 m-rows (one per 32-lane half).
// kernel staged in LDS as kl[k][f][o] (conflict-free); xs rows staged fp32 in LDS.

__global__ __launch_bounds__(256) void cheb_gemm(const ushort4* __restrict__ x0b,
                                                 const ushort4* __restrict__ x1b,
                                                 const ushort4* __restrict__ x2b,
                                                 const ushort4* __restrict__ x3b,
                                                 const ushort4* __restrict__ x4b,
                                                 const float* __restrict__ kern,
                                                 const float* __restrict__ bias,
                                                 float* __restrict__ out) {
  __shared__ float kl[K][FIN][F1];   // 10 KB
  __shared__ float xl[8][K][FB];     // 40 KB: 8 m-rows per block
  int tid = threadIdx.x;
  for (int i = tid; i < K * FIN * F1; i += 256) {
    int o = i & 31, rest = i >> 5;
    int f = rest & 15, k = rest >> 4;
    kl[k][f][o] = kern[(f * K + k) * F1 + o];
  }
  int wave = tid >> 6, lane = tid & 63;
  int h = lane >> 5, o = lane & 31;
  int m0 = blockIdx.x * 8 + 2 * wave;

#pragma unroll
  for (int s = 0; s < 2; ++s) {
    size_t m = m0 + s;
    int slot = 2 * wave + s;
    *(float4*)(&xl[slot][0][lane * 4]) = bf4(x0b[m * RW + lane]);
    *(float4*)(&xl[slot][1][lane * 4]) = bf4(x1b[m * RW + lane]);
    *(float4*)(&xl[slot][2][lane * 4]) = bf4(x2b[m * RW + lane]);
    *(float4*)(&xl[slot][3][lane * 4]) = bf4(x3b[m * RW + lane]);
    *(float4*)(&xl[slot][4][lane * 4]) = bf4(x4b[m * RW + lane]);
  }
  __syncthreads();

  float acc[16];
  float bs = bias[o];
#pragma unroll
  for (int b = 0; b < 16; ++b) acc[b] = bs;

  int slot = 2 * wave + h;
#pragma unroll
  for (int k = 0; k < K; ++k) {
#pragma unroll
    for (int f4 = 0; f4 < 4; ++f4) {
      float kv0 = kl[k][f4 * 4 + 0][o];
      float kv1 = kl[k][f4 * 4 + 1][o];
      float kv2 = kl[k][f4 * 4 + 2][o];
      float kv3 = kl[k][f4 * 4 + 3][o];
#pragma unroll
      for (int b = 0; b < 16; ++b) {
        const float4 xv = *(const float4*)(&xl[slot][k][b * 16 + f4 * 4]);
        acc[b] = fmaf(xv.x, kv0, acc[b]);
        acc[b] = fmaf(xv.y, kv1, acc[b]);
        acc[b] = fmaf(xv.z, kv2, acc[b]);
        acc[b] = fmaf(xv.w, kv3, acc[b]);
      }
    }
  }

  int m = m0 + h;
#pragma unroll
  for (int b = 0; b < 16; ++b)
    out[((size_t)b * M + m) * F1 + o] = acc[b];
}

// ---------------- launch ----------------

extern "C" void kernel_launch(void* const* d_in, const int* in_sizes, int n_in,
                              void* d_out, int out_size, void* d_ws, size_t ws_size,
                              hipStream_t stream) {
  const float* x    = (const float*)d_in[0];
  const int*   rows = (const int*)d_in[1];
  const int*   cols = (const int*)d_in[2];
  const float* vals = (const float*)d_in[3];
  const float* kern = (const float*)d_in[4];
  const float* bias = (const float*)d_in[5];
  float* out = (float*)d_out;
  int nnz = in_sizes[1];

  // workspace layout (~130 MiB)
  const size_t BUF = (size_t)M * RW;              // ushort4 count per buffer
  ushort4* x0b = (ushort4*)d_ws;
  ushort4* x1b = x0b + BUF;
  ushort4* x2b = x1b + BUF;
  ushort4* x3b = x2b + BUF;
  ushort4* x4b = x3b + BUF;
  int* row_ptr  = (int*)(x4b + BUF);              // M+1 (padded)
  int* counts   = row_ptr + (M + 256);            // M (doubles as scatter fill)
  int* partials = counts + M;                     // 48 (padded to 256)
  int2* cv      = (int2*)(partials + 256);        // NNZ packed (col, val)

  int nblk1024 = M / 1024;                        // 48
  int nblkNnz  = (nnz + 255) / 256;

  transform_x<<<M / 4, 256, 0, stream>>>(x, x0b);

  hipMemsetAsync(counts, 0, (size_t)M * 4, stream);
  hist_kernel<<<nblkNnz, 256, 0, stream>>>(rows, counts, nnz);
  scan_blocks<<<nblk1024, 1024, 0, stream>>>(counts, row_ptr, partials);
  scan_partials_kernel<<<1, 64, 0, stream>>>(partials, row_ptr, nblk1024);
  scan_add_kernel<<<nblk1024, 1024, 0, stream>>>(row_ptr, partials);
  hipMemsetAsync(counts, 0, (size_t)M * 4, stream);
  scatter_kernel<<<nblkNnz, 256, 0, stream>>>(rows, cols, vals, row_ptr, counts, cv, nnz);

  // Chebyshev recurrence (all bf16 operands, fp32 accumulate)
  spmm_bf16<false><<<M / 4, 256, 0, stream>>>(x0b, nullptr, x1b, row_ptr, cv);
  spmm_bf16<true ><<<M / 4, 256, 0, stream>>>(x1b, x0b, x2b, row_ptr, cv);
  spmm_bf16<true ><<<M / 4, 256, 0, stream>>>(x2b, x1b, x3b, row_ptr, cv);
  spmm_bf16<true ><<<M / 4, 256, 0, stream>>>(x3b, x2b, x4b, row_ptr, cv);

  // final contraction + bias
  cheb_gemm<<<M / 8, 256, 0, stream>>>(x0b, x1b, x2b, x3b, x4b, kern, bias, out);

  (void)n_in; (void)out_size; (void)ws_size; (void)in_sizes;
}

// Round 3
// 274.532 us; speedup vs baseline: 1.7603x; 1.3218x over previous
//
#include <hip/hip_runtime.h>

// GraphConvolution (Chebyshev K=5) on MI355X — round 3.
// Change vs round 2: final contraction done with MFMA (bf16 16x16x32) instead
// of a VALU/LDS-bound vector gemm (was 95 us, VALUBusy 65%, occupancy 30%).
// A = xs (already bf16 in ws, 5 contiguous buffers), B = kernel -> bf16 LDS
// fragment table. kk=(k,f) padded 80 -> 96 = 3 MFMA chunks.
// Also: SpMM edge loop unrolled x2 (2 gathers in flight), CSR memsets merged.

constexpr int M   = 49152;
constexpr int B   = 16;
constexpr int FIN = 16;
constexpr int F1  = 32;
constexpr int K   = 5;
constexpr int FB  = B * FIN;            // 256 features per internal row
constexpr int RW  = FB / 4;             // 64 ushort4 per row
constexpr int XBS = M * FIN;            // per-b stride in x[B,M,FIN]

typedef short s16x8 __attribute__((ext_vector_type(8)));
typedef float f32x4 __attribute__((ext_vector_type(4)));

#define DEVFN __device__ __forceinline__

DEVFN float bf2f(unsigned short h) {
  union { unsigned int u; float f; } v;
  v.u = (unsigned int)h << 16;
  return v.f;
}
DEVFN unsigned short f2bf(float f) {   // round-to-nearest-even
  union { float f; unsigned int u; } v;
  v.f = f;
  unsigned int r = (v.u + 0x7FFFu + ((v.u >> 16) & 1u)) >> 16;
  return (unsigned short)r;
}
DEVFN float4 bf4(ushort4 u) {
  return make_float4(bf2f(u.x), bf2f(u.y), bf2f(u.z), bf2f(u.w));
}

// ---------------- x -> bf16 [M][256] ----------------

__global__ __launch_bounds__(256) void transform_x(const float* __restrict__ x,
                                                   ushort4* __restrict__ x0b) {
  int lane = threadIdx.x & 63;
  int m = blockIdx.x * 4 + (threadIdx.x >> 6);
  int b = lane >> 2, f0 = (lane & 3) * 4;
  float4 v = *(const float4*)(x + (size_t)b * XBS + (size_t)m * FIN + f0);
  x0b[(size_t)m * RW + lane] = make_ushort4(f2bf(v.x), f2bf(v.y), f2bf(v.z), f2bf(v.w));
}

// ---------------- CSR build ----------------

__global__ __launch_bounds__(256) void hist_kernel(const int* __restrict__ rows,
                                                   int* __restrict__ counts, int nnz) {
  int i = blockIdx.x * 256 + threadIdx.x;
  if (i < nnz) atomicAdd(&counts[rows[i]], 1);
}

DEVFN int wave_incl_scan(int v, int lane) {
#pragma unroll
  for (int off = 1; off < 64; off <<= 1) {
    int t = __shfl_up(v, off);
    if (lane >= off) v += t;
  }
  return v;
}

__global__ __launch_bounds__(1024) void scan_blocks(const int* __restrict__ counts,
                                                    int* __restrict__ row_ptr,
                                                    int* __restrict__ partials) {
  __shared__ int wsum[16];
  int tid = threadIdx.x, lane = tid & 63, w = tid >> 6;
  int i = blockIdx.x * 1024 + tid;
  int s = wave_incl_scan(counts[i], lane);
  if (lane == 63) wsum[w] = s;
  __syncthreads();
  if (tid < 16) {
    int t = wsum[tid];
#pragma unroll
    for (int off = 1; off < 16; off <<= 1) {
      int u = __shfl_up(t, off);
      if (tid >= off) t += u;
    }
    wsum[tid] = t;
  }
  __syncthreads();
  int base = (w > 0) ? wsum[w - 1] : 0;
  s += base;
  row_ptr[i + 1] = s;
  if (tid == 1023) partials[blockIdx.x] = s;
}

__global__ void scan_partials_kernel(int* __restrict__ partials,
                                     int* __restrict__ row_ptr, int nblk) {
  int lane = threadIdx.x;  // 64 threads
  int v = (lane < nblk) ? partials[lane] : 0;
  v = wave_incl_scan(v, lane);
  if (lane < nblk) partials[lane] = v;
  if (lane == 0) row_ptr[0] = 0;
}

__global__ __launch_bounds__(1024) void scan_add_kernel(int* __restrict__ row_ptr,
                                                        const int* __restrict__ partials) {
  if (blockIdx.x == 0) return;
  int i = blockIdx.x * 1024 + threadIdx.x;
  row_ptr[i + 1] += partials[blockIdx.x - 1];
}

__global__ __launch_bounds__(256) void scatter_kernel(const int* __restrict__ rows,
                                                      const int* __restrict__ cols,
                                                      const float* __restrict__ vals,
                                                      const int* __restrict__ row_ptr,
                                                      int* __restrict__ fill,
                                                      int2* __restrict__ cv, int nnz) {
  int i = blockIdx.x * 256 + threadIdx.x;
  if (i < nnz) {
    int r = rows[i];
    int pos = row_ptr[r] + atomicAdd(&fill[r], 1);
    cv[pos] = make_int2(cols[i], __float_as_int(vals[i]));
  }
}

// ---------------- SpMM (one wave per output row, bf16 rows) ----------------

template <bool SUB>
__global__ __launch_bounds__(256) void spmm_bf16(const ushort4* __restrict__ gsrc,
                                                 const ushort4* __restrict__ ssrc,
                                                 ushort4* __restrict__ y,
                                                 const int* __restrict__ row_ptr,
                                                 const int2* __restrict__ cv) {
  int lane = threadIdx.x & 63;
  int m = blockIdx.x * 4 + (threadIdx.x >> 6);
  int beg = row_ptr[m], end = row_ptr[m + 1];
  float a0 = 0.f, a1 = 0.f, a2 = 0.f, a3 = 0.f;
  int e = beg;
  for (; e + 2 <= end; e += 2) {           // 2 independent gathers in flight
    int2 p0 = cv[e];
    int2 p1 = cv[e + 1];
    ushort4 xv0 = gsrc[(size_t)p0.x * RW + lane];
    ushort4 xv1 = gsrc[(size_t)p1.x * RW + lane];
    float v0 = __int_as_float(p0.y);
    float v1 = __int_as_float(p1.y);
    a0 = fmaf(v0, bf2f(xv0.x), a0);
    a1 = fmaf(v0, bf2f(xv0.y), a1);
    a2 = fmaf(v0, bf2f(xv0.z), a2);
    a3 = fmaf(v0, bf2f(xv0.w), a3);
    a0 = fmaf(v1, bf2f(xv1.x), a0);
    a1 = fmaf(v1, bf2f(xv1.y), a1);
    a2 = fmaf(v1, bf2f(xv1.z), a2);
    a3 = fmaf(v1, bf2f(xv1.w), a3);
  }
  if (e < end) {
    int2 p = cv[e];
    float v = __int_as_float(p.y);
    ushort4 xv = gsrc[(size_t)p.x * RW + lane];
    a0 = fmaf(v, bf2f(xv.x), a0);
    a1 = fmaf(v, bf2f(xv.y), a1);
    a2 = fmaf(v, bf2f(xv.z), a2);
    a3 = fmaf(v, bf2f(xv.w), a3);
  }
  if (SUB) {
    float4 s = bf4(ssrc[(size_t)m * RW + lane]);
    a0 = fmaf(2.f, a0, -s.x);
    a1 = fmaf(2.f, a1, -s.y);
    a2 = fmaf(2.f, a2, -s.z);
    a3 = fmaf(2.f, a3, -s.w);
  }
  y[(size_t)m * RW + lane] = make_ushort4(f2bf(a0), f2bf(a1), f2bf(a2), f2bf(a3));
}

// ---------------- Final contraction via MFMA ----------------
// out[(b*M+m)*32+o] = sum_{k,f} xs_k[m][b*16+f] * kern[(f*5+k)*32+o] + bias[o]
// A[row=m-local][kk], B[kk][o], kk = c*32 + g*8 + j  <->  k = 2c+(g>>1),
// f = (g&1)*8 + j.  3 chunks of K=32 (kk 80..95 zero).
// mfma_f32_16x16x32_bf16: A lane l holds A[l&15][(l>>4)*8+j] (16B contiguous);
// B lane l holds B[(l>>4)*8+j][l&15]; C/D: col=l&15, row=(l>>4)*4+reg.

__global__ __launch_bounds__(256) void cheb_gemm_mfma(const ushort4* __restrict__ xs0,
                                                      const float* __restrict__ kern,
                                                      const float* __restrict__ bias,
                                                      float* __restrict__ out) {
  __shared__ unsigned short bl[3][4][32][8];  // [c][g][o][j] = B_kk,o  (6 KB)
  __shared__ float bsl[32];
  int tid = threadIdx.x;
  for (int idx = tid; idx < 3 * 4 * 32 * 8; idx += 256) {
    int j = idx & 7, o = (idx >> 3) & 31, g = (idx >> 8) & 3, c = idx >> 10;
    int k = 2 * c + (g >> 1), f = (g & 1) * 8 + j;
    bl[c][g][o][j] = (k < K) ? f2bf(kern[(f * K + k) * F1 + o]) : (unsigned short)0;
  }
  if (tid < 32) bsl[tid] = bias[tid];
  __syncthreads();

  int lane = tid & 63;
  int w = blockIdx.x * 4 + (tid >> 6);     // 0..6143
  int b = w / 384;                         // 384 waves per batch b
  int mt0 = (w % 384) * 8;                 // first 16-row m-tile of 8

  int row = lane & 15, g = lane >> 4;
  int col = lane & 15;

  // B fragments (constant per wave)
  s16x8 bf[3][2];
#pragma unroll
  for (int c = 0; c < 3; ++c) {
#pragma unroll
    for (int ot = 0; ot < 2; ++ot)
      bf[c][ot] = *(const s16x8*)(&bl[c][g][col + 16 * ot][0]);
  }
  float bias0 = bsl[col], bias1 = bsl[col + 16];

  const char* xsbase = (const char*)xs0;
  const size_t BUFBYTES = (size_t)M * 512;
  size_t lanebyte = (size_t)row * 512 + (size_t)b * 32 + (size_t)(g & 1) * 16;
  int khalf = g >> 1;
  const char* p0 = xsbase + (size_t)(0 + khalf) * BUFBYTES + lanebyte;
  const char* p1 = xsbase + (size_t)(2 + khalf) * BUFBYTES + lanebyte;
  const char* p2 = xsbase + (size_t)(4 + khalf) * BUFBYTES + lanebyte;  // valid g<2

  size_t obase0 = ((size_t)b * M + (size_t)mt0 * 16) * F1;

#pragma unroll 2
  for (int t = 0; t < 8; ++t) {
    size_t moff = (size_t)(mt0 + t) * (16 * 512);
    s16x8 a0 = *(const s16x8*)(p0 + moff);
    s16x8 a1 = *(const s16x8*)(p1 + moff);
    s16x8 a2 = (g < 2) ? *(const s16x8*)(p2 + moff) : (s16x8)0;

    f32x4 acc0 = {0.f, 0.f, 0.f, 0.f};
    f32x4 acc1 = {0.f, 0.f, 0.f, 0.f};
    acc0 = __builtin_amdgcn_mfma_f32_16x16x32_bf16(a0, bf[0][0], acc0, 0, 0, 0);
    acc1 = __builtin_amdgcn_mfma_f32_16x16x32_bf16(a0, bf[0][1], acc1, 0, 0, 0);
    acc0 = __builtin_amdgcn_mfma_f32_16x16x32_bf16(a1, bf[1][0], acc0, 0, 0, 0);
    acc1 = __builtin_amdgcn_mfma_f32_16x16x32_bf16(a1, bf[1][1], acc1, 0, 0, 0);
    acc0 = __builtin_amdgcn_mfma_f32_16x16x32_bf16(a2, bf[2][0], acc0, 0, 0, 0);
    acc1 = __builtin_amdgcn_mfma_f32_16x16x32_bf16(a2, bf[2][1], acc1, 0, 0, 0);

    float* ob = out + obase0 + (size_t)t * (16 * F1);
#pragma unroll
    for (int j = 0; j < 4; ++j) {
      int r = g * 4 + j;
      ob[r * F1 + col]      = acc0[j] + bias0;
      ob[r * F1 + col + 16] = acc1[j] + bias1;
    }
  }
}

// ---------------- launch ----------------

extern "C" void kernel_launch(void* const* d_in, const int* in_sizes, int n_in,
                              void* d_out, int out_size, void* d_ws, size_t ws_size,
                              hipStream_t stream) {
  const float* x    = (const float*)d_in[0];
  const int*   rows = (const int*)d_in[1];
  const int*   cols = (const int*)d_in[2];
  const float* vals = (const float*)d_in[3];
  const float* kern = (const float*)d_in[4];
  const float* bias = (const float*)d_in[5];
  float* out = (float*)d_out;
  int nnz = in_sizes[1];

  // workspace layout (~130 MiB); x0b..x4b MUST stay contiguous (gemm indexes
  // buffer k as xsbase + k*M*512 bytes).
  const size_t BUF = (size_t)M * RW;              // ushort4 count per buffer
  ushort4* x0b = (ushort4*)d_ws;
  ushort4* x1b = x0b + BUF;
  ushort4* x2b = x1b + BUF;
  ushort4* x3b = x2b + BUF;
  ushort4* x4b = x3b + BUF;
  int* row_ptr  = (int*)(x4b + BUF);              // M+1 (padded)
  int* counts   = row_ptr + (M + 256);            // M
  int* fill     = counts + M;                     // M (scatter cursor)
  int* partials = fill + M;                       // 48 (padded to 256)
  int2* cv      = (int2*)(partials + 256);        // NNZ packed (col, val)

  int nblk1024 = M / 1024;                        // 48
  int nblkNnz  = (nnz + 255) / 256;

  transform_x<<<M / 4, 256, 0, stream>>>(x, x0b);

  hipMemsetAsync(counts, 0, (size_t)2 * M * 4, stream);   // counts + fill
  hist_kernel<<<nblkNnz, 256, 0, stream>>>(rows, counts, nnz);
  scan_blocks<<<nblk1024, 1024, 0, stream>>>(counts, row_ptr, partials);
  scan_partials_kernel<<<1, 64, 0, stream>>>(partials, row_ptr, nblk1024);
  scan_add_kernel<<<nblk1024, 1024, 0, stream>>>(row_ptr, partials);
  scatter_kernel<<<nblkNnz, 256, 0, stream>>>(rows, cols, vals, row_ptr, fill, cv, nnz);

  // Chebyshev recurrence (bf16 operands, fp32 accumulate)
  spmm_bf16<false><<<M / 4, 256, 0, stream>>>(x0b, nullptr, x1b, row_ptr, cv);
  spmm_bf16<true ><<<M / 4, 256, 0, stream>>>(x1b, x0b, x2b, row_ptr, cv);
  spmm_bf16<true ><<<M / 4, 256, 0, stream>>>(x2b, x1b, x3b, row_ptr, cv);
  spmm_bf16<true ><<<M / 4, 256, 0, stream>>>(x3b, x2b, x4b, row_ptr, cv);

  // final contraction + bias via MFMA: 1536 blocks x 4 waves x 8 m-tiles
  cheb_gemm_mfma<<<1536, 256, 0, stream>>>(x0b, kern, bias, out);

  (void)n_in; (void)out_size; (void)ws_size; (void)in_sizes;
}

// Round 4
// 258.493 us; speedup vs baseline: 1.8695x; 1.0620x over previous
//
#include <hip/hip_runtime.h>

// GraphConvolution (Chebyshev K=5) on MI355X — round 4.
// Change vs round 3: SpMM restructured for gather concurrency. Each edge's
// 512 B bf16 row is now fetched by a HALF-wave at 16 B/lane (2 edges per
// instruction per wave), and 4 pair-iterations are unrolled -> up to 8 edges
// (= mean degree) in flight per wave, vs 2 before. Cross-half reduce is
// 8x shfl_xor(32) per row. Probes whether the ~3.4 TB/s gather rate was an
// outstanding-request limit or a true random-access BW ceiling.

constexpr int M   = 49152;
constexpr int B   = 16;
constexpr int FIN = 16;
constexpr int F1  = 32;
constexpr int K   = 5;
constexpr int FB  = B * FIN;            // 256 bf16 features per internal row
constexpr int RW  = FB / 4;             // 64 ushort4 per row
constexpr int ROWBYTES = FB * 2;        // 512 B per row
constexpr int XBS = M * FIN;            // per-b stride in x[B,M,FIN]

typedef short s16x8 __attribute__((ext_vector_type(8)));
typedef float f32x4 __attribute__((ext_vector_type(4)));

#define DEVFN __device__ __forceinline__

DEVFN float bf2f(unsigned short h) {
  union { unsigned int u; float f; } v;
  v.u = (unsigned int)h << 16;
  return v.f;
}
DEVFN unsigned short f2bf(float f) {   // round-to-nearest-even
  union { float f; unsigned int u; } v;
  v.f = f;
  unsigned int r = (v.u + 0x7FFFu + ((v.u >> 16) & 1u)) >> 16;
  return (unsigned short)r;
}

// ---------------- x -> bf16 [M][256] ----------------

__global__ __launch_bounds__(256) void transform_x(const float* __restrict__ x,
                                                   ushort4* __restrict__ x0b) {
  int lane = threadIdx.x & 63;
  int m = blockIdx.x * 4 + (threadIdx.x >> 6);
  int b = lane >> 2, f0 = (lane & 3) * 4;
  float4 v = *(const float4*)(x + (size_t)b * XBS + (size_t)m * FIN + f0);
  x0b[(size_t)m * RW + lane] = make_ushort4(f2bf(v.x), f2bf(v.y), f2bf(v.z), f2bf(v.w));
}

// ---------------- CSR build ----------------

__global__ __launch_bounds__(256) void hist_kernel(const int* __restrict__ rows,
                                                   int* __restrict__ counts, int nnz) {
  int i = blockIdx.x * 256 + threadIdx.x;
  if (i < nnz) atomicAdd(&counts[rows[i]], 1);
}

DEVFN int wave_incl_scan(int v, int lane) {
#pragma unroll
  for (int off = 1; off < 64; off <<= 1) {
    int t = __shfl_up(v, off);
    if (lane >= off) v += t;
  }
  return v;
}

__global__ __launch_bounds__(1024) void scan_blocks(const int* __restrict__ counts,
                                                    int* __restrict__ row_ptr,
                                                    int* __restrict__ partials) {
  __shared__ int wsum[16];
  int tid = threadIdx.x, lane = tid & 63, w = tid >> 6;
  int i = blockIdx.x * 1024 + tid;
  int s = wave_incl_scan(counts[i], lane);
  if (lane == 63) wsum[w] = s;
  __syncthreads();
  if (tid < 16) {
    int t = wsum[tid];
#pragma unroll
    for (int off = 1; off < 16; off <<= 1) {
      int u = __shfl_up(t, off);
      if (tid >= off) t += u;
    }
    wsum[tid] = t;
  }
  __syncthreads();
  int base = (w > 0) ? wsum[w - 1] : 0;
  s += base;
  row_ptr[i + 1] = s;
  if (tid == 1023) partials[blockIdx.x] = s;
}

__global__ void scan_partials_kernel(int* __restrict__ partials,
                                     int* __restrict__ row_ptr, int nblk) {
  int lane = threadIdx.x;  // 64 threads
  int v = (lane < nblk) ? partials[lane] : 0;
  v = wave_incl_scan(v, lane);
  if (lane < nblk) partials[lane] = v;
  if (lane == 0) row_ptr[0] = 0;
}

__global__ __launch_bounds__(1024) void scan_add_kernel(int* __restrict__ row_ptr,
                                                        const int* __restrict__ partials) {
  if (blockIdx.x == 0) return;
  int i = blockIdx.x * 1024 + threadIdx.x;
  row_ptr[i + 1] += partials[blockIdx.x - 1];
}

__global__ __launch_bounds__(256) void scatter_kernel(const int* __restrict__ rows,
                                                      const int* __restrict__ cols,
                                                      const float* __restrict__ vals,
                                                      const int* __restrict__ row_ptr,
                                                      int* __restrict__ fill,
                                                      int2* __restrict__ cv, int nnz) {
  int i = blockIdx.x * 256 + threadIdx.x;
  if (i < nnz) {
    int r = rows[i];
    int pos = row_ptr[r] + atomicAdd(&fill[r], 1);
    cv[pos] = make_int2(cols[i], __float_as_int(vals[i]));
  }
}

// ---------------- SpMM: one wave per row, 2 edges per gather instr ----------
// lane: half = lane>>5 (which edge of a pair), fl = lane&31 (16-B feature
// chunk: features fl*8 .. fl*8+7). Unroll 4 pairs -> 8 edges in flight.
// After the edge loop, halves are summed via shfl_xor(32); half 0 applies the
// Chebyshev sub and stores the bf16 row.

template <bool SUB>
__global__ __launch_bounds__(256) void spmm_pair(const ushort4* __restrict__ gsrc_,
                                                 const ushort4* __restrict__ ssrc_,
                                                 ushort4* __restrict__ y_,
                                                 const int* __restrict__ row_ptr,
                                                 const int2* __restrict__ cv) {
  const char* gsrc = (const char*)gsrc_;
  int lane = threadIdx.x & 63;
  int half = lane >> 5, fl = lane & 31;
  int m = blockIdx.x * 4 + (threadIdx.x >> 6);
  int beg = row_ptr[m], end = row_ptr[m + 1];
  int n = end - beg;

  float acc[8];
#pragma unroll
  for (int j = 0; j < 8; ++j) acc[j] = 0.f;

  size_t fb = (size_t)fl * 16;
  int e = beg + half;
  int t8 = n >> 3;                     // uniform across the wave
  for (int t = 0; t < t8; ++t, e += 8) {
    int2 p[4];
    s16x8 xv[4];
#pragma unroll
    for (int u = 0; u < 4; ++u) p[u] = cv[e + 2 * u];
#pragma unroll
    for (int u = 0; u < 4; ++u)
      xv[u] = *(const s16x8*)(gsrc + (size_t)p[u].x * ROWBYTES + fb);
#pragma unroll
    for (int u = 0; u < 4; ++u) {
      float v = __int_as_float(p[u].y);
#pragma unroll
      for (int j = 0; j < 8; ++j)
        acc[j] = fmaf(v, bf2f((unsigned short)xv[u][j]), acc[j]);
    }
  }
  for (; e < end; e += 2) {            // tail (divergent between halves only)
    int2 p = cv[e];
    s16x8 xv = *(const s16x8*)(gsrc + (size_t)p.x * ROWBYTES + fb);
    float v = __int_as_float(p.y);
#pragma unroll
    for (int j = 0; j < 8; ++j)
      acc[j] = fmaf(v, bf2f((unsigned short)xv[j]), acc[j]);
  }

  // combine the two halves
#pragma unroll
  for (int j = 0; j < 8; ++j) acc[j] += __shfl_xor(acc[j], 32);

  if (half == 0) {
    if (SUB) {
      s16x8 sv = *(const s16x8*)((const char*)ssrc_ + (size_t)m * ROWBYTES + fb);
#pragma unroll
      for (int j = 0; j < 8; ++j)
        acc[j] = fmaf(2.f, acc[j], -bf2f((unsigned short)sv[j]));
    }
    s16x8 r;
#pragma unroll
    for (int j = 0; j < 8; ++j) r[j] = (short)f2bf(acc[j]);
    *(s16x8*)((char*)y_ + (size_t)m * ROWBYTES + fb) = r;
  }
}

// ---------------- Final contraction via MFMA ----------------
// out[(b*M+m)*32+o] = sum_{k,f} xs_k[m][b*16+f] * kern[(f*5+k)*32+o] + bias[o]
// kk = c*32 + g*8 + j <-> k = 2c+(g>>1), f = (g&1)*8+j; 3 chunks of K=32.

__global__ __launch_bounds__(256) void cheb_gemm_mfma(const ushort4* __restrict__ xs0,
                                                      const float* __restrict__ kern,
                                                      const float* __restrict__ bias,
                                                      float* __restrict__ out) {
  __shared__ unsigned short bl[3][4][32][8];  // [c][g][o][j] = B_kk,o  (6 KB)
  __shared__ float bsl[32];
  int tid = threadIdx.x;
  for (int idx = tid; idx < 3 * 4 * 32 * 8; idx += 256) {
    int j = idx & 7, o = (idx >> 3) & 31, g = (idx >> 8) & 3, c = idx >> 10;
    int k = 2 * c + (g >> 1), f = (g & 1) * 8 + j;
    bl[c][g][o][j] = (k < K) ? f2bf(kern[(f * K + k) * F1 + o]) : (unsigned short)0;
  }
  if (tid < 32) bsl[tid] = bias[tid];
  __syncthreads();

  int lane = tid & 63;
  int w = blockIdx.x * 4 + (tid >> 6);     // 0..6143
  int b = w / 384;                         // 384 waves per batch b
  int mt0 = (w % 384) * 8;                 // first 16-row m-tile of 8

  int row = lane & 15, g = lane >> 4;
  int col = lane & 15;

  s16x8 bf[3][2];
#pragma unroll
  for (int c = 0; c < 3; ++c) {
#pragma unroll
    for (int ot = 0; ot < 2; ++ot)
      bf[c][ot] = *(const s16x8*)(&bl[c][g][col + 16 * ot][0]);
  }
  float bias0 = bsl[col], bias1 = bsl[col + 16];

  const char* xsbase = (const char*)xs0;
  const size_t BUFBYTES = (size_t)M * ROWBYTES;
  size_t lanebyte = (size_t)row * ROWBYTES + (size_t)b * 32 + (size_t)(g & 1) * 16;
  int khalf = g >> 1;
  const char* p0 = xsbase + (size_t)(0 + khalf) * BUFBYTES + lanebyte;
  const char* p1 = xsbase + (size_t)(2 + khalf) * BUFBYTES + lanebyte;
  const char* p2 = xsbase + (size_t)(4 + khalf) * BUFBYTES + lanebyte;  // valid g<2

  size_t obase0 = ((size_t)b * M + (size_t)mt0 * 16) * F1;

#pragma unroll 2
  for (int t = 0; t < 8; ++t) {
    size_t moff = (size_t)(mt0 + t) * (16 * ROWBYTES);
    s16x8 a0 = *(const s16x8*)(p0 + moff);
    s16x8 a1 = *(const s16x8*)(p1 + moff);
    s16x8 a2 = (g < 2) ? *(const s16x8*)(p2 + moff) : (s16x8)0;

    f32x4 acc0 = {0.f, 0.f, 0.f, 0.f};
    f32x4 acc1 = {0.f, 0.f, 0.f, 0.f};
    acc0 = __builtin_amdgcn_mfma_f32_16x16x32_bf16(a0, bf[0][0], acc0, 0, 0, 0);
    acc1 = __builtin_amdgcn_mfma_f32_16x16x32_bf16(a0, bf[0][1], acc1, 0, 0, 0);
    acc0 = __builtin_amdgcn_mfma_f32_16x16x32_bf16(a1, bf[1][0], acc0, 0, 0, 0);
    acc1 = __builtin_amdgcn_mfma_f32_16x16x32_bf16(a1, bf[1][1], acc1, 0, 0, 0);
    acc0 = __builtin_amdgcn_mfma_f32_16x16x32_bf16(a2, bf[2][0], acc0, 0, 0, 0);
    acc1 = __builtin_amdgcn_mfma_f32_16x16x32_bf16(a2, bf[2][1], acc1, 0, 0, 0);

    float* ob = out + obase0 + (size_t)t * (16 * F1);
#pragma unroll
    for (int j = 0; j < 4; ++j) {
      int r = g * 4 + j;
      ob[r * F1 + col]      = acc0[j] + bias0;
      ob[r * F1 + col + 16] = acc1[j] + bias1;
    }
  }
}

// ---------------- launch ----------------

extern "C" void kernel_launch(void* const* d_in, const int* in_sizes, int n_in,
                              void* d_out, int out_size, void* d_ws, size_t ws_size,
                              hipStream_t stream) {
  const float* x    = (const float*)d_in[0];
  const int*   rows = (const int*)d_in[1];
  const int*   cols = (const int*)d_in[2];
  const float* vals = (const float*)d_in[3];
  const float* kern = (const float*)d_in[4];
  const float* bias = (const float*)d_in[5];
  float* out = (float*)d_out;
  int nnz = in_sizes[1];

  // workspace layout (~130 MiB); x0b..x4b MUST stay contiguous (gemm indexes
  // buffer k as xsbase + k*M*512 bytes).
  const size_t BUF = (size_t)M * RW;              // ushort4 count per buffer
  ushort4* x0b = (ushort4*)d_ws;
  ushort4* x1b = x0b + BUF;
  ushort4* x2b = x1b + BUF;
  ushort4* x3b = x2b + BUF;
  ushort4* x4b = x3b + BUF;
  int* row_ptr  = (int*)(x4b + BUF);              // M+1 (padded)
  int* counts   = row_ptr + (M + 256);            // M
  int* fill     = counts + M;                     // M (scatter cursor)
  int* partials = fill + M;                       // 48 (padded to 256)
  int2* cv      = (int2*)(partials + 256);        // NNZ packed (col, val)

  int nblk1024 = M / 1024;                        // 48
  int nblkNnz  = (nnz + 255) / 256;

  transform_x<<<M / 4, 256, 0, stream>>>(x, x0b);

  hipMemsetAsync(counts, 0, (size_t)2 * M * 4, stream);   // counts + fill
  hist_kernel<<<nblkNnz, 256, 0, stream>>>(rows, counts, nnz);
  scan_blocks<<<nblk1024, 1024, 0, stream>>>(counts, row_ptr, partials);
  scan_partials_kernel<<<1, 64, 0, stream>>>(partials, row_ptr, nblk1024);
  scan_add_kernel<<<nblk1024, 1024, 0, stream>>>(row_ptr, partials);
  scatter_kernel<<<nblkNnz, 256, 0, stream>>>(rows, cols, vals, row_ptr, fill, cv, nnz);

  // Chebyshev recurrence (bf16 operands, fp32 accumulate)
  spmm_pair<false><<<M / 4, 256, 0, stream>>>(x0b, nullptr, x1b, row_ptr, cv);
  spmm_pair<true ><<<M / 4, 256, 0, stream>>>(x1b, x0b, x2b, row_ptr, cv);
  spmm_pair<true ><<<M / 4, 256, 0, stream>>>(x2b, x1b, x3b, row_ptr, cv);
  spmm_pair<true ><<<M / 4, 256, 0, stream>>>(x3b, x2b, x4b, row_ptr, cv);

  // final contraction + bias via MFMA: 1536 blocks x 4 waves x 8 m-tiles
  cheb_gemm_mfma<<<1536, 256, 0, stream>>>(x0b, kern, bias, out);

  (void)n_in; (void)out_size; (void)ws_size; (void)in_sizes;
}